// Round 1
// baseline (947.347 us; speedup 1.0000x reference)
//
#include <hip/hip_runtime.h>
#include <stdint.h>

// SparseUvuTensorProduct on MI355X.
// B=32768 rows, IN_DIM=2048, OUT_DIM=2432, MUL=128.
// Groups: g0 = path(d=1,mode0); g1..g3 = (mode0 path, mode1 path) pairs sharing the
// same x1 region (d=3,5,7). Each block: TB=16 rows of one group.

#define IN_DIM 2048
#define OUT_DIM 2432
#define TB 16
#define SROW 136        // LDS row stride (bf16 elems) for x2s/scal
#define PLANE 2184      // LDS dd-plane stride for x2s: 16*136+8 (breaks bank aliasing)
#define TPAD 129        // fp32 row stride for tmp/mixed1

using bf16x8 = __attribute__((ext_vector_type(8))) short;  // 8 bf16 in 4 VGPRs
using f32x4  = __attribute__((ext_vector_type(4))) float;

__device__ __forceinline__ short f2bf(float f) {
  uint32_t u = __float_as_uint(f);
  uint32_t r = (u + 0x7fffu + ((u >> 16) & 1u)) >> 16;
  return (short)r;
}

__device__ __forceinline__ bf16x8 pack8(float4 lo, float4 hi) {
  bf16x8 r;
  r[0] = f2bf(lo.x); r[1] = f2bf(lo.y); r[2] = f2bf(lo.z); r[3] = f2bf(lo.w);
  r[4] = f2bf(hi.x); r[5] = f2bf(hi.y); r[6] = f2bf(hi.z); r[7] = f2bf(hi.w);
  return r;
}

template <int D, bool HASM1>
__device__ __forceinline__ void run_group(
    const float* __restrict__ x1, const float* __restrict__ x2,
    const float* __restrict__ w, const float* __restrict__ mask,
    float* __restrict__ out,
    int tile, int rs, int outs0, int w0off, int outs1, int w1off, float inv,
    short* x2s, short* scal, float* tmp, float* mixed1)
{
  const int t   = threadIdx.x;
  const int L   = t & 63;
  const int wid = t >> 6;        // wave id 0..3
  const int l16 = L & 15;
  const int kg  = L >> 4;        // k-group 0..3 (8 k's each)
  const int b0  = tile * TB;

  // ---- stage x2v tile -> LDS as bf16 [dd][b][v] (transposed for k-contiguous frags)
  for (int i = t; i < TB * 128 * D; i += 256) {
    int b  = i / (128 * D);
    int c  = i - b * (128 * D);
    int v  = c / D;
    int dd = c - v * D;
    float val = x2[(size_t)(b0 + b) * IN_DIM + rs + c];
    x2s[dd * PLANE + b * SROW + v] = f2bf(val);
  }
  if (HASM1) {
    // mode1 scalars = x2[:, 0:128]
    for (int i = t; i < TB * 128; i += 256) {
      int b = i >> 7, v = i & 127;
      scal[b * SROW + v] = f2bf(x2[(size_t)(b0 + b) * IN_DIM + v]);
    }
  }
  __syncthreads();

  // ---- mode1 GEMM: mixed1[b,u] = sum_v scal[b,v] * W1[u,v]
  if (HASM1) {
    bf16x8 a4[4];
#pragma unroll
    for (int k = 0; k < 4; k++)
      a4[k] = *(const bf16x8*)&scal[l16 * SROW + kg * 8 + k * 32];
#pragma unroll
    for (int ti = 0; ti < 2; ti++) {
      int ut = (wid * 2 + ti) * 16 + l16;   // this lane's u (B-operand n index)
      f32x4 acc = {0.f, 0.f, 0.f, 0.f};
#pragma unroll
      for (int k = 0; k < 4; k++) {
        const float4* p = (const float4*)(w + w1off + ut * 128 + kg * 8 + k * 32);
        bf16x8 bf = pack8(p[0], p[1]);
        acc = __builtin_amdgcn_mfma_f32_16x16x32_bf16(a4[k], bf, acc, 0, 0, 0);
      }
#pragma unroll
      for (int r = 0; r < 4; r++)   // row = b = kg*4+r, col = u
        mixed1[(kg * 4 + r) * TPAD + (wid * 2 + ti) * 16 + l16] = acc[r];
    }
  }

  // ---- W0 fragments into VGPRs (reused across all D chunks)
  bf16x8 w0f[2][4];
#pragma unroll
  for (int ti = 0; ti < 2; ti++) {
    int ut = (wid * 2 + ti) * 16 + l16;     // A-operand m index = u
#pragma unroll
    for (int k = 0; k < 4; k++) {
      const float4* p = (const float4*)(w + w0off + ut * 128 + kg * 8 + k * 32);
      w0f[ti][k] = pack8(p[0], p[1]);
    }
  }

  const int uu = t & 127;   // step2 mapping: lane-consecutive u for coalescing
  const int hb = t >> 7;
  float m0acc[8];
#pragma unroll
  for (int i = 0; i < 8; i++) m0acc[i] = 0.f;

  // ---- mode0 chunks: one dd per chunk
  for (int dd = 0; dd < D; dd++) {
    // prefetch this chunk's x1 values early (independent of LDS/barrier)
    float xv[8];
#pragma unroll
    for (int i = 0; i < 8; i++) {
      int b = 2 * i + hb;
      xv[i] = x1[(size_t)(b0 + b) * IN_DIM + rs + uu * D + dd];
    }

    bf16x8 bfr[4];
#pragma unroll
    for (int k = 0; k < 4; k++)
      bfr[k] = *(const bf16x8*)&x2s[dd * PLANE + l16 * SROW + kg * 8 + k * 32];
#pragma unroll
    for (int ti = 0; ti < 2; ti++) {
      f32x4 acc = {0.f, 0.f, 0.f, 0.f};
#pragma unroll
      for (int k = 0; k < 4; k++)
        acc = __builtin_amdgcn_mfma_f32_16x16x32_bf16(w0f[ti][k], bfr[k], acc, 0, 0, 0);
      // D[m=u][n=b]: row u = ti_tile*16 + kg*4 + r, col b = l16 -> tmp[b][u]
#pragma unroll
      for (int r = 0; r < 4; r++)
        tmp[l16 * TPAD + (wid * 2 + ti) * 16 + kg * 4 + r] = acc[r];
    }
    __syncthreads();

#pragma unroll
    for (int i = 0; i < 8; i++) {
      int b = 2 * i + hb;
      m0acc[i] += xv[i] * tmp[b * TPAD + uu];
    }
    __syncthreads();
  }

  // ---- mode0 epilogue: out[:, outs0 + u]
  {
    float mk0 = mask[outs0 + uu] * inv;
#pragma unroll
    for (int i = 0; i < 8; i++) {
      int b = 2 * i + hb;
      out[(size_t)(b0 + b) * OUT_DIM + outs0 + uu] = m0acc[i] * mk0;
    }
  }

  // ---- mode1 epilogue: out[:, outs1 + u*D + dd] = x1v * mixed1 * inv * mask
  if (HASM1) {
    float mkv[D];
#pragma unroll
    for (int dd = 0; dd < D; dd++) mkv[dd] = mask[outs1 + uu * D + dd] * inv;
#pragma unroll
    for (int i = 0; i < 8; i++) {
      int b = 2 * i + hb;
      float m1 = mixed1[b * TPAD + uu];
#pragma unroll
      for (int dd = 0; dd < D; dd++) {
        float xv = x1[(size_t)(b0 + b) * IN_DIM + rs + uu * D + dd];
        out[(size_t)(b0 + b) * OUT_DIM + outs1 + uu * D + dd] = xv * m1 * mkv[dd];
      }
    }
  }
}

__global__ void __launch_bounds__(256, 3)
tp_kernel(const float* __restrict__ x1, const float* __restrict__ x2,
          const float* __restrict__ w, const float* __restrict__ mask,
          float* __restrict__ out)
{
  __shared__ __align__(16) short x2s[7 * PLANE];    // 30.6 KB
  __shared__ __align__(16) short scal[TB * SROW];   //  4.4 KB
  __shared__ __align__(16) float tmp[TB * TPAD];    //  8.3 KB
  __shared__ __align__(16) float mixed1[TB * TPAD]; //  8.3 KB

  int bx   = blockIdx.x;
  int g    = bx & 3;        // interleave groups for L2 reuse of x2[:, :128]
  int tile = bx >> 2;

  switch (g) {
    case 0:
      run_group<1, false>(x1, x2, w, mask, out, tile, 0, 0, 0 * 16384, 0, 0,
                          1.0f, x2s, scal, tmp, mixed1);
      break;
    case 1:
      run_group<3, true>(x1, x2, w, mask, out, tile, 128, 128, 1 * 16384, 512, 4 * 16384,
                         0.5773502691896258f, x2s, scal, tmp, mixed1);
      break;
    case 2:
      run_group<5, true>(x1, x2, w, mask, out, tile, 512, 256, 2 * 16384, 896, 5 * 16384,
                         0.4472135954999579f, x2s, scal, tmp, mixed1);
      break;
    case 3:
      run_group<7, true>(x1, x2, w, mask, out, tile, 1152, 384, 3 * 16384, 1536, 6 * 16384,
                         0.3779644730092272f, x2s, scal, tmp, mixed1);
      break;
  }
}

extern "C" void kernel_launch(void* const* d_in, const int* in_sizes, int n_in,
                              void* d_out, int out_size, void* d_ws, size_t ws_size,
                              hipStream_t stream) {
  const float* x1   = (const float*)d_in[0];
  const float* x2   = (const float*)d_in[1];
  const float* w    = (const float*)d_in[2];
  const float* mask = (const float*)d_in[3];
  float* out = (float*)d_out;

  dim3 grid(4 * (32768 / TB));  // 8192 blocks: (tile, group) interleaved
  dim3 block(256);
  tp_kernel<<<grid, block, 0, stream>>>(x1, x2, w, mask, out);
}